// Round 15
// baseline (73.367 us; speedup 1.0000x reference)
//
#include <hip/hip_runtime.h>
#include <math.h>

#define ALPHA 0.3f
#define KN 32

__device__ __forceinline__ float leaky_f(float x) { return x >= 0.f ? x : ALPHA * x; }

// lane-broadcast via v_readlane (VALU pipe -- NOT the DS unit)
__device__ __forceinline__ float rl(float x, int l) {
    return __int_as_float(__builtin_amdgcn_readlane(__float_as_int(x), l));
}
__device__ __forceinline__ int rli(int x, int l) {
    return __builtin_amdgcn_readlane(x, l);
}
// wave-uniform row pointer -> SGPR base so row[c] becomes s_load (SMEM pipe)
__device__ __forceinline__ const float* urow(const float* base, int row) {
    return base + (size_t)__builtin_amdgcn_readfirstlane(row) * 64;
}

// ---------------------------------------------------------------------------
// K_A: 8 nodes/block (grid 1500 -> max in-flight random gathers):
//   h0[n,h] = leaky( sum_c emb[n,c]*Q0w[c,h] + Q0b[h] )   (2 nodes per wave)
//   wcache[n,k] = wmat[n, nbr[n,k]]   (1 entry/thread, issued FIRST)
// ZERO LDS. x rows read via the SCALAR pipe (wave-uniform rows).
// ---------------------------------------------------------------------------
__global__ __launch_bounds__(256) void k_dense_gather(
    const float* __restrict__ X,
    const float* __restrict__ Qw,
    const float* __restrict__ Qb,
    const float* __restrict__ wmat,
    const int*  __restrict__ nbr,
    float* __restrict__ wcache,      // may be null
    float* __restrict__ Hout,
    int N)
{
    const int tid  = threadIdx.x;
    const int wid  = tid >> 6;
    const int lane = tid & 63;
    const int bs   = blockIdx.x * 8;

    // --- random gather: 256 (node,k) entries = 1 per thread, issued first ---
    int gn = bs + (tid >> 5); if (gn >= N) gn = N - 1;
    const int   gid = nbr[(size_t)gn * KN + (tid & 31)];
    const float gw  = wmat[(size_t)gn * (size_t)N + gid];

    // --- own 2 x-rows via scalar pipe ---
    const int n0 = bs + wid * 2;
    const int n1 = n0 + 1;
    const int m0 = n0 < N ? n0 : N - 1;
    const int m1 = n1 < N ? n1 : N - 1;
    const float* x0 = urow(X, m0);
    const float* x1 = urow(X, m1);

    // --- dense GEMV: Q row (L1-hot) shared; x from SGPRs (no readlane) ---
    const float qb = Qb[lane];
    float a0 = qb, a1 = qb;
    #pragma unroll
    for (int c = 0; c < 64; ++c) {
        float qv = Qw[c * 64 + lane];
        a0 = fmaf(x0[c], qv, a0);
        a1 = fmaf(x1[c], qv, a1);
    }
    if (n0 < N) Hout[(size_t)n0 * 64 + lane] = leaky_f(a0);
    if (n1 < N) Hout[(size_t)n1 * 64 + lane] = leaky_f(a1);

    // --- persist gathered weights (coalesced, 1 float/thread) ---
    if (wcache && bs + (tid >> 5) < N)
        wcache[(size_t)bs * KN + tid] = gw;
}

// ---------------------------------------------------------------------------
// K_B/K_C: conv layer, 16 nodes/block = 4 waves x 4 CONCURRENT nodes (quad).
// ZERO LDS. Gather entries in 2 regs; entry (j,k) at reg j>>1, lane (j&1)*32+k.
// W/Q row loads (global, L1-hot) shared by 4 nodes. x rows via SCALAR pipe.
//   agg_j = sum_k w_jk*Hbuf[id_jk,:]/(sum_k w_jk+1e-6)
//   o_j = leaky([x_j,agg_j].Ww + Wb); OUT = o/(||o||+1e-6)
//   FUSE: H1out_j = leaky(OUT_j.Q1w + Q1b)
// In-place safe (OUT may alias X): each block reads only its own rows (scalar
// loads, 256B-aligned rows so no cache-line sharing) before writing them.
// ---------------------------------------------------------------------------
template<bool FUSE>
__global__ __launch_bounds__(256) void k_conv(
    const float* __restrict__ X,
    const float* __restrict__ Hbuf,
    const float* __restrict__ Wmat,
    const float* __restrict__ wcache,
    const int*  __restrict__ nbr,
    const float* __restrict__ Ww,    // 128 x 64
    const float* __restrict__ Wb,
    const float* __restrict__ Q1w,   // 64 x 64 (FUSE)
    const float* __restrict__ Q1b,   // 64     (FUSE)
    float* __restrict__ OUT,
    float* __restrict__ H1out,
    int N, int mode)
{
    const int tid  = threadIdx.x;
    const int wid  = tid >> 6;
    const int lane = tid & 63;
    const int bs   = blockIdx.x * 16;
    const int nbase = bs + wid * 4;

    // --- issue all irregular loads FIRST ---
    int   gid0, gid1; float gw0, gw1;
    {
        int e0 = lane,      n0 = nbase + (e0 >> 5);
        int e1 = 64 + lane, n1 = nbase + (e1 >> 5);
        if (n0 >= N) n0 = N - 1;
        if (n1 >= N) n1 = N - 1;
        gid0 = nbr[(size_t)n0 * KN + (e0 & 31)];
        gid1 = nbr[(size_t)n1 * KN + (e1 & 31)];
        if (mode == 1) {
            gw0 = wcache[(size_t)n0 * KN + (e0 & 31)];
            gw1 = wcache[(size_t)n1 * KN + (e1 & 31)];
        } else {
            gw0 = Wmat[(size_t)n0 * (size_t)N + gid0];
            gw1 = Wmat[(size_t)n1 * (size_t)N + gid1];
        }
    }
    // own 4 x-rows via scalar pipe
    int p0 = nbase + 0; if (p0 >= N) p0 = N - 1;
    int p1 = nbase + 1; if (p1 >= N) p1 = N - 1;
    int p2 = nbase + 2; if (p2 >= N) p2 = N - 1;
    int p3 = nbase + 3; if (p3 >= N) p3 = N - 1;
    const float* xr0 = urow(X, p0);
    const float* xr1 = urow(X, p1);
    const float* xr2 = urow(X, p2);
    const float* xr3 = urow(X, p3);

    // --- sum of weights per node (32-lane-half butterflies) ---
    float s0 = gw0, s1 = gw1;
    #pragma unroll
    for (int off = 16; off; off >>= 1) {
        s0 += __shfl_xor(s0, off);
        s1 += __shfl_xor(s1, off);
    }
    const float sumw0 = rl(s0, 0);
    const float sumw1 = rl(s0, 32);
    const float sumw2 = rl(s1, 0);
    const float sumw3 = rl(s1, 32);

    // --- neighbor aggregation: entry (j,k) via readlane (compile-time src) ---
    float ag0 = 0.f, ag1 = 0.f, ag2 = 0.f, ag3 = 0.f;
    #pragma unroll
    for (int k = 0; k < KN; ++k) {
        int   i0 = rli(gid0, k);        float w0 = rl(gw0, k);
        int   i1 = rli(gid0, 32 + k);   float w1 = rl(gw0, 32 + k);
        int   i2 = rli(gid1, k);        float w2 = rl(gw1, k);
        int   i3 = rli(gid1, 32 + k);   float w3 = rl(gw1, 32 + k);
        ag0 = fmaf(w0, Hbuf[(size_t)i0 * 64 + lane], ag0);
        ag1 = fmaf(w1, Hbuf[(size_t)i1 * 64 + lane], ag1);
        ag2 = fmaf(w2, Hbuf[(size_t)i2 * 64 + lane], ag2);
        ag3 = fmaf(w3, Hbuf[(size_t)i3 * 64 + lane], ag3);
    }
    const float sa0 = ag0 / (sumw0 + 1e-6f);
    const float sa1 = ag1 / (sumw1 + 1e-6f);
    const float sa2 = ag2 / (sumw2 + 1e-6f);
    const float sa3 = ag3 / (sumw3 + 1e-6f);

    // --- combine GEMV: W row shared by 4 nodes; x from SGPRs ---
    const float wb = Wb[lane];
    float ac0 = wb, ac1 = wb, ac2 = wb, ac3 = wb;
    #pragma unroll
    for (int c = 0; c < 64; ++c) {
        float wv = Ww[c * 64 + lane];
        ac0 = fmaf(xr0[c], wv, ac0);
        ac1 = fmaf(xr1[c], wv, ac1);
        ac2 = fmaf(xr2[c], wv, ac2);
        ac3 = fmaf(xr3[c], wv, ac3);
    }
    #pragma unroll
    for (int c = 0; c < 64; ++c) {
        float wv = Ww[(64 + c) * 64 + lane];
        ac0 = fmaf(rl(sa0, c), wv, ac0);
        ac1 = fmaf(rl(sa1, c), wv, ac1);
        ac2 = fmaf(rl(sa2, c), wv, ac2);
        ac3 = fmaf(rl(sa3, c), wv, ac3);
    }

    // --- leaky + L2 normalize + write ---
    float o0 = leaky_f(ac0), o1 = leaky_f(ac1);
    float o2 = leaky_f(ac2), o3 = leaky_f(ac3);
    float q0 = o0 * o0, q1 = o1 * o1, q2 = o2 * o2, q3 = o3 * o3;
    #pragma unroll
    for (int off = 32; off; off >>= 1) {
        q0 += __shfl_xor(q0, off);
        q1 += __shfl_xor(q1, off);
        q2 += __shfl_xor(q2, off);
        q3 += __shfl_xor(q3, off);
    }
    const float on0 = o0 / (sqrtf(q0) + 1e-6f);
    const float on1 = o1 / (sqrtf(q1) + 1e-6f);
    const float on2 = o2 / (sqrtf(q2) + 1e-6f);
    const float on3 = o3 / (sqrtf(q3) + 1e-6f);
    if (nbase + 0 < N) OUT[(size_t)(nbase + 0) * 64 + lane] = on0;
    if (nbase + 1 < N) OUT[(size_t)(nbase + 1) * 64 + lane] = on1;
    if (nbase + 2 < N) OUT[(size_t)(nbase + 2) * 64 + lane] = on2;
    if (nbase + 3 < N) OUT[(size_t)(nbase + 3) * 64 + lane] = on3;

    // --- FUSE: h1 = leaky(out0 . Q1 + b); Q row shared by 4 nodes ---
    if (FUSE) {
        const float qb = Q1b[lane];
        float b0 = qb, b1 = qb, b2 = qb, b3 = qb;
        #pragma unroll
        for (int c = 0; c < 64; ++c) {
            float qv = Q1w[c * 64 + lane];
            b0 = fmaf(rl(on0, c), qv, b0);
            b1 = fmaf(rl(on1, c), qv, b1);
            b2 = fmaf(rl(on2, c), qv, b2);
            b3 = fmaf(rl(on3, c), qv, b3);
        }
        if (nbase + 0 < N) H1out[(size_t)(nbase + 0) * 64 + lane] = leaky_f(b0);
        if (nbase + 1 < N) H1out[(size_t)(nbase + 1) * 64 + lane] = leaky_f(b1);
        if (nbase + 2 < N) H1out[(size_t)(nbase + 2) * 64 + lane] = leaky_f(b2);
        if (nbase + 3 < N) H1out[(size_t)(nbase + 3) * 64 + lane] = leaky_f(b3);
    }
}

extern "C" void kernel_launch(void* const* d_in, const int* in_sizes, int n_in,
                              void* d_out, int out_size, void* d_ws, size_t ws_size,
                              hipStream_t stream)
{
    const float* emb  = (const float*)d_in[0];  // (1, N, 64)
    const float* wmat = (const float*)d_in[1];  // (N, N)
    const int*   nbr  = (const int*)  d_in[2];  // (N, 32) int32
    const float* Q0w  = (const float*)d_in[3];
    const float* Q0b  = (const float*)d_in[4];
    const float* W0w  = (const float*)d_in[5];
    const float* W0b  = (const float*)d_in[6];
    const float* Q1w  = (const float*)d_in[7];
    const float* Q1b  = (const float*)d_in[8];
    const float* W1w  = (const float*)d_in[9];
    const float* W1b  = (const float*)d_in[10];
    float* out = (float*)d_out;

    const int N = in_sizes[2] / KN;             // 12000
    const size_t hbuf_bytes = (size_t)N * 64 * sizeof(float);
    const size_t wc_bytes   = (size_t)N * KN * sizeof(float);

    float* h0 = (float*)d_ws;
    float* h1 = (float*)((char*)d_ws + hbuf_bytes);
    bool use_wc = ws_size >= 2 * hbuf_bytes + wc_bytes;
    float* wcache = use_wc ? (float*)((char*)d_ws + 2 * hbuf_bytes) : nullptr;
    const int mode = use_wc ? 1 : 0;

    const int gridA = (N + 7) / 8;     // 1500: max in-flight random gathers
    const int gridC = (N + 15) / 16;   // 750: quad-sharing convs

    // K_A: h0 + wcache (gather overlapped with dense GEMV)
    k_dense_gather<<<gridA, 256, 0, stream>>>(emb, Q0w, Q0b, wmat, nbr,
                                              wcache, h0, N);
    // K_B: layer-0 conv (+ fused layer-1 dense): emb,h0 -> out0, h1
    k_conv<true><<<gridC, 256, 0, stream>>>(emb, h0, wmat, wcache, nbr,
                                            W0w, W0b, Q1w, Q1b, out, h1, N, mode);
    // K_C: layer-1 conv (in-place on out)
    k_conv<false><<<gridC, 256, 0, stream>>>(out, h1, wmat, wcache, nbr,
                                             W1w, W1b, nullptr, nullptr,
                                             out, nullptr, N, mode);
}

// Round 16
// 54.518 us; speedup vs baseline: 1.3458x; 1.3458x over previous
//
#include <hip/hip_runtime.h>
#include <math.h>

#define ALPHA 0.3f
#define KN 32

__device__ __forceinline__ float leaky_f(float x) { return x >= 0.f ? x : ALPHA * x; }

// lane-broadcast via v_readlane (VALU pipe -- NOT the DS unit)
__device__ __forceinline__ float rl(float x, int l) {
    return __int_as_float(__builtin_amdgcn_readlane(__float_as_int(x), l));
}
__device__ __forceinline__ int rli(int x, int l) {
    return __builtin_amdgcn_readlane(x, l);
}

// ---------------------------------------------------------------------------
// K_A: 8 nodes/block (grid 1500 -> max in-flight random gathers):
//   h0[n,h] = leaky( sum_c emb[n,c]*Q0w[c,h] + Q0b[h] )   (2 nodes per wave)
//   wcache[n,k] = wmat[n, nbr[n,k]]   (1 entry/thread, issued FIRST)
// ZERO LDS.
// ---------------------------------------------------------------------------
__global__ __launch_bounds__(256) void k_dense_gather(
    const float* __restrict__ X,
    const float* __restrict__ Qw,
    const float* __restrict__ Qb,
    const float* __restrict__ wmat,
    const int*  __restrict__ nbr,
    float* __restrict__ wcache,      // may be null
    float* __restrict__ Hout,
    int N)
{
    const int tid  = threadIdx.x;
    const int wid  = tid >> 6;
    const int lane = tid & 63;
    const int bs   = blockIdx.x * 8;

    // --- random gather: 256 (node,k) entries = 1 per thread, issued first ---
    int gn = bs + (tid >> 5); if (gn >= N) gn = N - 1;
    const int   gid = nbr[(size_t)gn * KN + (tid & 31)];
    const float gw  = wmat[(size_t)gn * (size_t)N + gid];

    // --- own 2 x-rows ---
    const int n0 = bs + wid * 2;
    const int n1 = n0 + 1;
    const int m0 = n0 < N ? n0 : N - 1;
    const int m1 = n1 < N ? n1 : N - 1;
    const float x0 = X[(size_t)m0 * 64 + lane];
    const float x1 = X[(size_t)m1 * 64 + lane];

    // --- dense GEMV: Q row (L1-hot) shared by both nodes ---
    const float qb = Qb[lane];
    float a0 = qb, a1 = qb;
    #pragma unroll
    for (int c = 0; c < 64; ++c) {
        float qv = Qw[c * 64 + lane];
        a0 = fmaf(rl(x0, c), qv, a0);
        a1 = fmaf(rl(x1, c), qv, a1);
    }
    if (n0 < N) Hout[(size_t)n0 * 64 + lane] = leaky_f(a0);
    if (n1 < N) Hout[(size_t)n1 * 64 + lane] = leaky_f(a1);

    // --- persist gathered weights (coalesced, 1 float/thread) ---
    if (wcache && bs + (tid >> 5) < N)
        wcache[(size_t)bs * KN + tid] = gw;
}

// ---------------------------------------------------------------------------
// K_B/K_C: conv layer, 16 nodes/block = 4 waves x 4 CONCURRENT nodes (quad).
// ZERO LDS. Gather entries in 2 regs: u=0 -> nodes {0,1}, u=1 -> nodes {2,3};
// entry (j,k) lives at reg u=j>>1, src-lane (j&1)*32+k  (compile-time).
// Every W/Q row load (global, L1-hot) is shared by 4 nodes.
//   agg_j = sum_k w_jk*Hbuf[id_jk,:]/(sum_k w_jk+1e-6)
//   o_j = leaky([x_j,agg_j].Ww + Wb); OUT = o/(||o||+1e-6)
//   FUSE: H1out_j = leaky(OUT_j.Q1w + Q1b)
// In-place safe (OUT may alias X): block reads only its own X rows, first.
// ---------------------------------------------------------------------------
template<bool FUSE>
__global__ __launch_bounds__(256) void k_conv(
    const float* __restrict__ X,
    const float* __restrict__ Hbuf,
    const float* __restrict__ Wmat,
    const float* __restrict__ wcache,
    const int*  __restrict__ nbr,
    const float* __restrict__ Ww,    // 128 x 64
    const float* __restrict__ Wb,
    const float* __restrict__ Q1w,   // 64 x 64 (FUSE)
    const float* __restrict__ Q1b,   // 64     (FUSE)
    float* __restrict__ OUT,
    float* __restrict__ H1out,
    int N, int mode)
{
    const int tid  = threadIdx.x;
    const int wid  = tid >> 6;
    const int lane = tid & 63;
    const int bs   = blockIdx.x * 16;
    const int nbase = bs + wid * 4;

    // --- issue all irregular loads FIRST ---
    // reg u holds entries e = u*64+lane: node j = e>>5, k = e&31
    int   gid0, gid1; float gw0, gw1;
    {
        int e0 = lane,      n0 = nbase + (e0 >> 5);
        int e1 = 64 + lane, n1 = nbase + (e1 >> 5);
        if (n0 >= N) n0 = N - 1;
        if (n1 >= N) n1 = N - 1;
        gid0 = nbr[(size_t)n0 * KN + (e0 & 31)];
        gid1 = nbr[(size_t)n1 * KN + (e1 & 31)];
        if (mode == 1) {
            gw0 = wcache[(size_t)n0 * KN + (e0 & 31)];
            gw1 = wcache[(size_t)n1 * KN + (e1 & 31)];
        } else {
            gw0 = Wmat[(size_t)n0 * (size_t)N + gid0];
            gw1 = Wmat[(size_t)n1 * (size_t)N + gid1];
        }
    }
    // own 4 x-rows
    float xr0, xr1, xr2, xr3;
    {
        int p0 = nbase + 0; if (p0 >= N) p0 = N - 1;
        int p1 = nbase + 1; if (p1 >= N) p1 = N - 1;
        int p2 = nbase + 2; if (p2 >= N) p2 = N - 1;
        int p3 = nbase + 3; if (p3 >= N) p3 = N - 1;
        xr0 = X[(size_t)p0 * 64 + lane];
        xr1 = X[(size_t)p1 * 64 + lane];
        xr2 = X[(size_t)p2 * 64 + lane];
        xr3 = X[(size_t)p3 * 64 + lane];
    }

    // --- sum of weights per node (32-lane-half butterflies on both regs) ---
    float s0 = gw0, s1 = gw1;
    #pragma unroll
    for (int off = 16; off; off >>= 1) {
        s0 += __shfl_xor(s0, off);
        s1 += __shfl_xor(s1, off);
    }
    const float sumw0 = rl(s0, 0);
    const float sumw1 = rl(s0, 32);
    const float sumw2 = rl(s1, 0);
    const float sumw3 = rl(s1, 32);

    // --- neighbor aggregation: entry (j,k) via readlane (compile-time src) ---
    float ag0 = 0.f, ag1 = 0.f, ag2 = 0.f, ag3 = 0.f;
    #pragma unroll
    for (int k = 0; k < KN; ++k) {
        int   i0 = rli(gid0, k);        float w0 = rl(gw0, k);
        int   i1 = rli(gid0, 32 + k);   float w1 = rl(gw0, 32 + k);
        int   i2 = rli(gid1, k);        float w2 = rl(gw1, k);
        int   i3 = rli(gid1, 32 + k);   float w3 = rl(gw1, 32 + k);
        ag0 = fmaf(w0, Hbuf[(size_t)i0 * 64 + lane], ag0);
        ag1 = fmaf(w1, Hbuf[(size_t)i1 * 64 + lane], ag1);
        ag2 = fmaf(w2, Hbuf[(size_t)i2 * 64 + lane], ag2);
        ag3 = fmaf(w3, Hbuf[(size_t)i3 * 64 + lane], ag3);
    }
    const float sa0 = ag0 / (sumw0 + 1e-6f);
    const float sa1 = ag1 / (sumw1 + 1e-6f);
    const float sa2 = ag2 / (sumw2 + 1e-6f);
    const float sa3 = ag3 / (sumw3 + 1e-6f);

    // --- combine GEMV: each W row load shared by 4 nodes ---
    const float wb = Wb[lane];
    float ac0 = wb, ac1 = wb, ac2 = wb, ac3 = wb;
    #pragma unroll
    for (int c = 0; c < 64; ++c) {
        float wv = Ww[c * 64 + lane];
        ac0 = fmaf(rl(xr0, c), wv, ac0);
        ac1 = fmaf(rl(xr1, c), wv, ac1);
        ac2 = fmaf(rl(xr2, c), wv, ac2);
        ac3 = fmaf(rl(xr3, c), wv, ac3);
    }
    #pragma unroll
    for (int c = 0; c < 64; ++c) {
        float wv = Ww[(64 + c) * 64 + lane];
        ac0 = fmaf(rl(sa0, c), wv, ac0);
        ac1 = fmaf(rl(sa1, c), wv, ac1);
        ac2 = fmaf(rl(sa2, c), wv, ac2);
        ac3 = fmaf(rl(sa3, c), wv, ac3);
    }

    // --- leaky + L2 normalize + write ---
    float o0 = leaky_f(ac0), o1 = leaky_f(ac1);
    float o2 = leaky_f(ac2), o3 = leaky_f(ac3);
    float q0 = o0 * o0, q1 = o1 * o1, q2 = o2 * o2, q3 = o3 * o3;
    #pragma unroll
    for (int off = 32; off; off >>= 1) {
        q0 += __shfl_xor(q0, off);
        q1 += __shfl_xor(q1, off);
        q2 += __shfl_xor(q2, off);
        q3 += __shfl_xor(q3, off);
    }
    const float on0 = o0 / (sqrtf(q0) + 1e-6f);
    const float on1 = o1 / (sqrtf(q1) + 1e-6f);
    const float on2 = o2 / (sqrtf(q2) + 1e-6f);
    const float on3 = o3 / (sqrtf(q3) + 1e-6f);
    if (nbase + 0 < N) OUT[(size_t)(nbase + 0) * 64 + lane] = on0;
    if (nbase + 1 < N) OUT[(size_t)(nbase + 1) * 64 + lane] = on1;
    if (nbase + 2 < N) OUT[(size_t)(nbase + 2) * 64 + lane] = on2;
    if (nbase + 3 < N) OUT[(size_t)(nbase + 3) * 64 + lane] = on3;

    // --- FUSE: h1 = leaky(out0 . Q1 + b); Q row shared by 4 nodes ---
    if (FUSE) {
        const float qb = Q1b[lane];
        float b0 = qb, b1 = qb, b2 = qb, b3 = qb;
        #pragma unroll
        for (int c = 0; c < 64; ++c) {
            float qv = Q1w[c * 64 + lane];
            b0 = fmaf(rl(on0, c), qv, b0);
            b1 = fmaf(rl(on1, c), qv, b1);
            b2 = fmaf(rl(on2, c), qv, b2);
            b3 = fmaf(rl(on3, c), qv, b3);
        }
        if (nbase + 0 < N) H1out[(size_t)(nbase + 0) * 64 + lane] = leaky_f(b0);
        if (nbase + 1 < N) H1out[(size_t)(nbase + 1) * 64 + lane] = leaky_f(b1);
        if (nbase + 2 < N) H1out[(size_t)(nbase + 2) * 64 + lane] = leaky_f(b2);
        if (nbase + 3 < N) H1out[(size_t)(nbase + 3) * 64 + lane] = leaky_f(b3);
    }
}

extern "C" void kernel_launch(void* const* d_in, const int* in_sizes, int n_in,
                              void* d_out, int out_size, void* d_ws, size_t ws_size,
                              hipStream_t stream)
{
    const float* emb  = (const float*)d_in[0];  // (1, N, 64)
    const float* wmat = (const float*)d_in[1];  // (N, N)
    const int*   nbr  = (const int*)  d_in[2];  // (N, 32) int32
    const float* Q0w  = (const float*)d_in[3];
    const float* Q0b  = (const float*)d_in[4];
    const float* W0w  = (const float*)d_in[5];
    const float* W0b  = (const float*)d_in[6];
    const float* Q1w  = (const float*)d_in[7];
    const float* Q1b  = (const float*)d_in[8];
    const float* W1w  = (const float*)d_in[9];
    const float* W1b  = (const float*)d_in[10];
    float* out = (float*)d_out;

    const int N = in_sizes[2] / KN;             // 12000
    const size_t hbuf_bytes = (size_t)N * 64 * sizeof(float);
    const size_t wc_bytes   = (size_t)N * KN * sizeof(float);

    float* h0 = (float*)d_ws;
    float* h1 = (float*)((char*)d_ws + hbuf_bytes);
    bool use_wc = ws_size >= 2 * hbuf_bytes + wc_bytes;
    float* wcache = use_wc ? (float*)((char*)d_ws + 2 * hbuf_bytes) : nullptr;
    const int mode = use_wc ? 1 : 0;

    const int gridA = (N + 7) / 8;     // 1500: max in-flight random gathers
    const int gridC = (N + 15) / 16;   // 750: quad-sharing convs

    // K_A: h0 + wcache (gather overlapped with dense GEMV)
    k_dense_gather<<<gridA, 256, 0, stream>>>(emb, Q0w, Q0b, wmat, nbr,
                                              wcache, h0, N);
    // K_B: layer-0 conv (+ fused layer-1 dense): emb,h0 -> out0, h1
    k_conv<true><<<gridC, 256, 0, stream>>>(emb, h0, wmat, wcache, nbr,
                                            W0w, W0b, Q1w, Q1b, out, h1, N, mode);
    // K_C: layer-1 conv (in-place on out)
    k_conv<false><<<gridC, 256, 0, stream>>>(out, h1, wmat, wcache, nbr,
                                             W1w, W1b, nullptr, nullptr,
                                             out, nullptr, N, mode);
}